// Round 21
// baseline (629.465 us; speedup 1.0000x reference)
//
#include <hip/hip_runtime.h>
#include <climits>

// R21: bucketed convoy scatter. Partition points into 16 buckets by
// (batch, qr>>8): each bucket's cell range is a contiguous ~1.64MB slice of
// g_cell that fits one XCD's 4MB L2. Scatter pins bucket bk to XCD bk&7
// (blockIdx%8 round-robin) so precheck reads become L2 hits.
static constexpr int kN = 8388608;
static constexpr int kNumCells = 3216822;   // > max real flat (2,560,800)
static constexpr int kNB = 16;

typedef float __attribute__((ext_vector_type(4))) f32x4;
typedef int   __attribute__((ext_vector_type(4))) i32x4;

__device__ __align__(16) unsigned long long g_cell[kNumCells]; // (hbits<<32)|~idx
__device__ __align__(16) unsigned long long g_keyb[kN];        // binned keys
__device__ __align__(16) unsigned g_flatb[kN];                 // binned flat idx
__device__ int g_minr = INT_MAX, g_maxr = INT_MIN;             // reset in fincell
__device__ int g_minc = INT_MAX, g_maxc = INT_MIN;
__device__ unsigned g_hist[kNB];                               // zero-init; reset in fincell
__device__ unsigned g_base[kNB + 1];
__device__ unsigned g_cursor[kNB];

__device__ __forceinline__ int quant(float v) {
    return (int)rintf(v * 40.0f);   // np-ref rule (proven R11/R12)
}
// Bucket from RAW (pre-min-subtraction) coords: bounds-free, maps to a
// contiguous flat range per bucket. Must be identical in hist and part.
__device__ __forceinline__ int bucket_of(int b, int qr) {
    int q = min(max(qr, 0), 1023);
    return ((b & 3) << 2) | (q >> 8);
}

// Fused: blocks [0,zb) zero cell+out (plain stores, R15-proven);
// blocks [zb,..) scan inputs once: minmax reduce + bucket histogram.
__global__ void k_prep(const float* __restrict__ xyz, const int* __restrict__ bidx,
                       int n, float* __restrict__ out, int total, int zb) {
    const int b = blockIdx.x;
    if (b < zb) {
        int t = b * blockDim.x + threadIdx.x;
        int S = zb * blockDim.x;
        uint4 z4 = make_uint4(0u, 0u, 0u, 0u);
        uint4* c4 = (uint4*)g_cell;
        const int nc4 = (int)(sizeof(g_cell) / 16);
        for (int i = t; i < nc4; i += S) c4[i] = z4;
        float4 f4 = make_float4(0.f, 0.f, 0.f, 0.f);
        float4* o4 = (float4*)out;
        const int no4 = total >> 2;
        for (int i = t; i < no4; i += S) o4[i] = f4;
        for (int i = (no4 << 2) + t; i < total; i += S) out[i] = 0.f;
        return;
    }
    __shared__ unsigned s_hist[kNB];
    if (threadIdx.x < kNB) s_hist[threadIdx.x] = 0;
    __syncthreads();
    const int t = (b - zb) * blockDim.x + threadIdx.x;
    const int S = (gridDim.x - zb) * blockDim.x;
    const int ngroups = n >> 2;
    const f32x4* p = (const f32x4*)xyz;
    int mnr = INT_MAX, mxr = INT_MIN, mnc = INT_MAX, mxc = INT_MIN;
    for (int g = t; g < ngroups; g += S) {
        f32x4 f0 = p[3 * g + 0];   // x0 h0 z0 x1
        f32x4 f1 = p[3 * g + 1];   // h1 z1 x2 h2
        f32x4 f2 = p[3 * g + 2];   // z2 x3 h3 z3
        i32x4 b4 = ((const i32x4*)bidx)[g];
        float xs[4] = {f0.x, f0.w, f1.z, f2.y};
        float zs[4] = {f0.z, f1.y, f2.x, f2.w};
        int bs[4] = {b4.x, b4.y, b4.z, b4.w};
#pragma unroll
        for (int j = 0; j < 4; ++j) {
            int qr = quant(zs[j]);
            int qc = quant(xs[j]);
            mnr = min(mnr, qr); mxr = max(mxr, qr);
            mnc = min(mnc, qc); mxc = max(mxc, qc);
            atomicAdd(&s_hist[bucket_of(bs[j], qr)], 1u);
        }
    }
    if (t == 0) {   // tail (absent for n = 2^23)
        for (int i = (ngroups << 2); i < n; ++i) {
            int qr = quant(xyz[3 * i + 2]);
            int qc = quant(xyz[3 * i + 0]);
            mnr = min(mnr, qr); mxr = max(mxr, qr);
            mnc = min(mnc, qc); mxc = max(mxc, qc);
            atomicAdd(&s_hist[bucket_of(bidx[i], qr)], 1u);
        }
    }
#pragma unroll
    for (int off = 32; off > 0; off >>= 1) {
        mnr = min(mnr, __shfl_down(mnr, off));
        mxr = max(mxr, __shfl_down(mxr, off));
        mnc = min(mnc, __shfl_down(mnc, off));
        mxc = max(mxc, __shfl_down(mxc, off));
    }
    __shared__ int s[4][4];
    int w = threadIdx.x >> 6;
    if ((threadIdx.x & 63) == 0) {
        s[w][0] = mnr; s[w][1] = mxr; s[w][2] = mnc; s[w][3] = mxc;
    }
    __syncthreads();
    if (threadIdx.x == 0) {
        int fmnr = min(min(s[0][0], s[1][0]), min(s[2][0], s[3][0]));
        int fmxr = max(max(s[0][1], s[1][1]), max(s[2][1], s[3][1]));
        int fmnc = min(min(s[0][2], s[1][2]), min(s[2][2], s[3][2]));
        int fmxc = max(max(s[0][3], s[1][3]), max(s[2][3], s[3][3]));
        atomicMin(&g_minr, fmnr); atomicMax(&g_maxr, fmxr);
        atomicMin(&g_minc, fmnc); atomicMax(&g_maxc, fmxc);
    }
    if (threadIdx.x < kNB && s_hist[threadIdx.x])
        atomicAdd(&g_hist[threadIdx.x], s_hist[threadIdx.x]);
}

__global__ void k_prefix() {
    if (threadIdx.x == 0 && blockIdx.x == 0) {
        unsigned acc = 0;
        for (int i = 0; i < kNB; ++i) {
            g_base[i] = acc; g_cursor[i] = acc; acc += g_hist[i];
        }
        g_base[kNB] = acc;
    }
}

// Partition: each block handles 2048 points; LDS bucket-sort its chunk, one
// global cursor atomicAdd per bucket per block, coalesced run copy-out.
__global__ void __launch_bounds__(256) k_part(const float* __restrict__ xyz,
                                              const int* __restrict__ bidx, int n) {
    __shared__ unsigned s_cnt[kNB], s_scan[kNB], s_gbase[kNB], s_lcur[kNB];
    __shared__ unsigned long long s_key[2048];
    __shared__ unsigned s_flat[2048];
    const int tid = threadIdx.x;
    const int chunk0 = blockIdx.x << 11;
    if (chunk0 >= n) return;
    const int minr = g_minr, minc = g_minc;
    const int rmax = g_maxr - minr, cmax = g_maxc - minc;
    if (tid < kNB) s_cnt[tid] = 0;
    __syncthreads();
    const int base = chunk0 + tid * 8;
    unsigned long long key[8]; unsigned fl[8]; int bk[8];
    int cntv = 0;
    if (base + 7 < n) {
        const f32x4* p = (const f32x4*)xyz;
        const i32x4* bp = (const i32x4*)bidx;
        float xs[8], hs[8], zs[8]; int bs[8];
        const int gg = (chunk0 >> 2) + tid * 2;
#pragma unroll
        for (int q = 0; q < 2; ++q) {
            f32x4 f0 = p[3 * (gg + q) + 0];
            f32x4 f1 = p[3 * (gg + q) + 1];
            f32x4 f2 = p[3 * (gg + q) + 2];
            xs[4*q+0]=f0.x; hs[4*q+0]=f0.y; zs[4*q+0]=f0.z;
            xs[4*q+1]=f0.w; hs[4*q+1]=f1.x; zs[4*q+1]=f1.y;
            xs[4*q+2]=f1.z; hs[4*q+2]=f1.w; zs[4*q+2]=f2.x;
            xs[4*q+3]=f2.y; hs[4*q+3]=f2.z; zs[4*q+3]=f2.w;
            i32x4 b4 = bp[gg + q];
            bs[4*q+0]=b4.x; bs[4*q+1]=b4.y; bs[4*q+2]=b4.z; bs[4*q+3]=b4.w;
        }
#pragma unroll
        for (int j = 0; j < 8; ++j) {
            int qr = quant(zs[j]);
            int qc = quant(xs[j]);
            bk[j] = bucket_of(bs[j], qr);
            int flat = bs[j] * (rmax * cmax) + (qr - minr) * cmax + (qc - minc);
            fl[j] = (flat >= 0 && flat < kNumCells) ? (unsigned)flat : 0xFFFFFFFFu;
            key[j] = ((unsigned long long)__float_as_uint(hs[j]) << 32)
                     | (unsigned)(~(base + j));
        }
        cntv = 8;
    } else if (base < n) {
        for (int i = base; i < n && i < base + 8; ++i) {
            int j = i - base;
            float x = xyz[3 * i + 0], h = xyz[3 * i + 1], z = xyz[3 * i + 2];
            int qr = quant(z), qc = quant(x);
            bk[j] = bucket_of(bidx[i], qr);
            int flat = bidx[i] * (rmax * cmax) + (qr - minr) * cmax + (qc - minc);
            fl[j] = (flat >= 0 && flat < kNumCells) ? (unsigned)flat : 0xFFFFFFFFu;
            key[j] = ((unsigned long long)__float_as_uint(h) << 32) | (unsigned)(~i);
            ++cntv;
        }
    }
    for (int j = 0; j < cntv; ++j) atomicAdd(&s_cnt[bk[j]], 1u);
    __syncthreads();
    if (tid == 0) {
        unsigned a = 0;
        for (int i = 0; i < kNB; ++i) { s_scan[i] = a; a += s_cnt[i]; }
    }
    __syncthreads();
    if (tid < kNB) {
        if (s_cnt[tid]) s_gbase[tid] = atomicAdd(&g_cursor[tid], s_cnt[tid]);
        s_lcur[tid] = s_scan[tid];
    }
    __syncthreads();
    for (int j = 0; j < cntv; ++j) {
        unsigned pos = atomicAdd(&s_lcur[bk[j]], 1u);
        s_key[pos] = key[j];
        s_flat[pos] = fl[j];
    }
    __syncthreads();
    for (int r = 0; r < kNB; ++r) {
        unsigned cnt = s_cnt[r];
        if (!cnt) continue;
        unsigned sb = s_scan[r], gb = s_gbase[r];
        for (unsigned i = tid; i < cnt; i += 256) {
            g_keyb[gb + i] = s_key[sb + i];
            g_flatb[gb + i] = s_flat[sb + i];
        }
    }
}

// XCD-pinned scatter: block bb -> XCD bb&7 (round-robin dispatch assumption,
// perf-only); XCD x processes buckets x and x+8 sequentially. Each bucket's
// cell slice (~1.64MB) stays L2-resident -> precheck reads hit L2.
// Precheck safety: cell values monotone non-decreasing; stale read <= truth
// => redundant atomic at worst; value > my key proves I lose => skip safe.
__global__ void __launch_bounds__(256) k_scatter() {
    const int bb = blockIdx.x;          // 2048 blocks
    const int xcd = bb & 7;
    const unsigned w = (unsigned)(bb >> 3);   // [0,256)
    for (int t = 0; t < 2; ++t) {
        const int bk = xcd + 8 * t;
        const unsigned lo = g_base[bk], hi = g_base[bk + 1];
        const unsigned long long len = hi - lo;
        unsigned a0 = lo + (unsigned)((len * w) >> 8);
        unsigned a1 = lo + (unsigned)((len * (w + 1)) >> 8);
        for (unsigned i = a0 + (unsigned)threadIdx.x * 4; i < a1; i += 256u * 4u) {
            unsigned long long kk[4]; unsigned ff[4];
            int m = (int)min(4u, a1 - i);
#pragma unroll
            for (int j = 0; j < 4; ++j) {
                if (j < m) { kk[j] = g_keyb[i + j]; ff[j] = g_flatb[i + j]; }
            }
            unsigned long long cur[4];
#pragma unroll
            for (int j = 0; j < 4; ++j)
                cur[j] = (j < m && ff[j] < (unsigned)kNumCells) ? g_cell[ff[j]] : ~0ULL;
#pragma unroll
            for (int j = 0; j < 4; ++j) {
                if (j < m && kk[j] > cur[j])
                    atomicMax(&g_cell[ff[j]], kk[j]);
            }
        }
    }
}

// Cell-centric finalize (out pre-zeroed in k_prep). Resets per-launch state
// (minmax scalars + histogram) for the next graph replay.
__global__ void k_fincell(int n, float* __restrict__ out) {
    if (blockIdx.x == 0) {
        if (threadIdx.x == 0) {
            g_minr = INT_MAX; g_maxr = INT_MIN;
            g_minc = INT_MAX; g_maxc = INT_MIN;
        }
        if (threadIdx.x < kNB) g_hist[threadIdx.x] = 0u;
    }
    int i = blockIdx.x * blockDim.x + threadIdx.x;
    int stride = gridDim.x * blockDim.x;
    for (int c = i; c < kNumCells; c += stride) {
        unsigned long long key = __builtin_nontemporal_load(&g_cell[c]);
        if (key == 0ULL) continue;          // empty (real keys have low word != 0)
        unsigned winner = ~(unsigned)key;   // min idx among max-height points
        float h = __uint_as_float((unsigned)(key >> 32));
        out[winner] = h;                    // [0,n) kept_heights
        out[n + winner] = 1.0f;             // [n,2n) keep
    }
}

extern "C" void kernel_launch(void* const* d_in, const int* in_sizes, int n_in,
                              void* d_out, int out_size, void* d_ws, size_t ws_size,
                              hipStream_t stream) {
    const float* xyz = (const float*)d_in[0];
    const int* bidx = (const int*)d_in[1];
    // d_in[2] (semantics) unused by the reference.
    int n = in_sizes[1];

    const int B = 256;
    int gridP = (n + 2047) >> 11;       // 4096 for n = 2^23
    k_prep<<<4096, B, 0, stream>>>(xyz, bidx, n, (float*)d_out, out_size, 1536);
    k_prefix<<<1, 64, 0, stream>>>();
    k_part<<<gridP, B, 0, stream>>>(xyz, bidx, n);
    k_scatter<<<2048, B, 0, stream>>>();
    k_fincell<<<4096, B, 0, stream>>>(n, (float*)d_out);
}

// Round 22
// 502.905 us; speedup vs baseline: 1.2517x; 1.2517x over previous
//
#include <hip/hip_runtime.h>
#include <climits>

// R22: no global atomics in the hot path. prep -> records; part -> 626
// cell-range buckets (4096 cells each); reduce -> per-block LDS two-phase
// (max hbits, then min idx) writing winners directly to out.
// Runtime-checked fast-path assumption: minr=minc=0, maxr=maxc=800 (true for
// this dataset); otherwise a gated R14-style fallback chain runs.
static constexpr int kN = 8388608;
static constexpr int kNumCells = 3216822;     // fb-path cell array bound
static constexpr int kMaxFlat = 2560800;      // 3*640000 + 800*800 + 800
static constexpr int kNBk = (kMaxFlat >> 12) + 1;   // 626 buckets x 4096 cells
static constexpr int kCap = 16384;            // bin capacity per bucket (~22% slack)

typedef float    __attribute__((ext_vector_type(4))) f32x4;
typedef int      __attribute__((ext_vector_type(4))) i32x4;
typedef unsigned long long __attribute__((ext_vector_type(2))) u64x2;

__device__ __align__(16) unsigned long long g_recs[kN];          // hbits<<32 | flat
__device__ __align__(16) unsigned long long g_keyb[kNBk * kCap]; // hbits<<32 | idx
__device__ __align__(16) unsigned short g_cellb[kNBk * kCap];    // flat & 4095
__device__ unsigned g_cursor[kNBk * 16];      // 64B-padded (1 line/bucket)
__device__ unsigned long long g_cell[kNumCells];                 // fb path only
__device__ int g_minr = INT_MAX, g_maxr = INT_MIN;
__device__ int g_minc = INT_MAX, g_maxc = INT_MIN;
__device__ int g_fb = 0;

__device__ __forceinline__ int quant(float v) {
    return (int)rintf(v * 40.0f);   // np-ref rule (proven R11/R12)
}
__device__ __forceinline__ bool okfast() {
    return g_minr == 0 && g_maxr == 800 && g_minc == 0 && g_maxc == 800;
}
__device__ __forceinline__ long long flat_assumed(int b, int qr, int qc) {
    long long f = (long long)b * 640000 + (long long)qr * 800 + qc;
    return f < 0 ? 0 : (f > kMaxFlat ? kMaxFlat : f);   // clamped only if !okfast
}

// Fused: blocks [0,zb) zero out; blocks [zb,..) scan: minmax + emit records.
__global__ void k_prep(const float* __restrict__ xyz, const int* __restrict__ bidx,
                       int n, float* __restrict__ out, int total, int zb) {
    const int b = blockIdx.x;
    if (b < zb) {
        int t = b * blockDim.x + threadIdx.x;
        int S = zb * blockDim.x;
        float4 f4 = make_float4(0.f, 0.f, 0.f, 0.f);
        float4* o4 = (float4*)out;
        const int no4 = total >> 2;
        for (int i = t; i < no4; i += S) o4[i] = f4;
        for (int i = (no4 << 2) + t; i < total; i += S) out[i] = 0.f;
        return;
    }
    const int t = (b - zb) * blockDim.x + threadIdx.x;
    const int S = (gridDim.x - zb) * blockDim.x;
    const int ngroups = n >> 2;
    const f32x4* p = (const f32x4*)xyz;
    u64x2* rp = (u64x2*)g_recs;
    int mnr = INT_MAX, mxr = INT_MIN, mnc = INT_MAX, mxc = INT_MIN;
    for (int g = t; g < ngroups; g += S) {
        f32x4 f0 = p[3 * g + 0];   // x0 h0 z0 x1
        f32x4 f1 = p[3 * g + 1];   // h1 z1 x2 h2
        f32x4 f2 = p[3 * g + 2];   // z2 x3 h3 z3
        i32x4 b4 = ((const i32x4*)bidx)[g];
        float xs[4] = {f0.x, f0.w, f1.z, f2.y};
        float hs[4] = {f0.y, f1.x, f1.w, f2.z};
        float zs[4] = {f0.z, f1.y, f2.x, f2.w};
        int bs[4] = {b4.x, b4.y, b4.z, b4.w};
        unsigned long long rr[4];
#pragma unroll
        for (int j = 0; j < 4; ++j) {
            int qr = quant(zs[j]);
            int qc = quant(xs[j]);
            mnr = min(mnr, qr); mxr = max(mxr, qr);
            mnc = min(mnc, qc); mxc = max(mxc, qc);
            long long fl = flat_assumed(bs[j], qr, qc);
            rr[j] = ((unsigned long long)__float_as_uint(hs[j]) << 32)
                  | (unsigned)fl;
        }
        u64x2 r01, r23;
        r01.x = rr[0]; r01.y = rr[1]; r23.x = rr[2]; r23.y = rr[3];
        rp[2 * g + 0] = r01;
        rp[2 * g + 1] = r23;
    }
    if (t == 0) {   // tail (absent for n = 2^23)
        for (int i = (ngroups << 2); i < n; ++i) {
            int qr = quant(xyz[3 * i + 2]);
            int qc = quant(xyz[3 * i + 0]);
            mnr = min(mnr, qr); mxr = max(mxr, qr);
            mnc = min(mnc, qc); mxc = max(mxc, qc);
            long long fl = flat_assumed(bidx[i], qr, qc);
            g_recs[i] = ((unsigned long long)__float_as_uint(xyz[3 * i + 1]) << 32)
                      | (unsigned)fl;
        }
    }
#pragma unroll
    for (int off = 32; off > 0; off >>= 1) {
        mnr = min(mnr, __shfl_down(mnr, off));
        mxr = max(mxr, __shfl_down(mxr, off));
        mnc = min(mnc, __shfl_down(mnc, off));
        mxc = max(mxc, __shfl_down(mxc, off));
    }
    __shared__ int s[4][4];
    int w = threadIdx.x >> 6;
    if ((threadIdx.x & 63) == 0) {
        s[w][0] = mnr; s[w][1] = mxr; s[w][2] = mnc; s[w][3] = mxc;
    }
    __syncthreads();
    if (threadIdx.x == 0) {
        atomicMin(&g_minr, min(min(s[0][0], s[1][0]), min(s[2][0], s[3][0])));
        atomicMax(&g_maxr, max(max(s[0][1], s[1][1]), max(s[2][1], s[3][1])));
        atomicMin(&g_minc, min(min(s[0][2], s[1][2]), min(s[2][2], s[3][2])));
        atomicMax(&g_maxc, max(max(s[0][3], s[1][3]), max(s[2][3], s[3][3])));
    }
}

__global__ void k_cursor() {
    int i = blockIdx.x * blockDim.x + threadIdx.x;
    if (i < kNBk) g_cursor[i << 4] = (unsigned)(i * kCap);
}

// Partition records into 626 cell-range buckets. 4096 pts/block, LDS staged,
// one padded-line cursor reservation per (block,bucket), wave-parallel copy-out.
__global__ void __launch_bounds__(256) k_part(int n) {
    if (!okfast()) {
        if (blockIdx.x == 0 && threadIdx.x == 0) g_fb = 1;
        return;
    }
    __shared__ unsigned s_cnt[kNBk], s_scan[kNBk], s_gbase[kNBk], s_lcur[kNBk];
    __shared__ unsigned long long s_key[4096];
    __shared__ unsigned short s_cell[4096];
    const int tid = threadIdx.x;
    const int chunk0 = blockIdx.x << 12;
    if (chunk0 >= n) return;
    for (int i = tid; i < kNBk; i += 256) s_cnt[i] = 0;
    __syncthreads();
    const int base = chunk0 + tid * 16;
    unsigned long long key[16];
    unsigned short cell[16], bk[16];
    int cnt = 0;
    if (base + 15 < n) {
        const u64x2* rp = (const u64x2*)g_recs;
#pragma unroll
        for (int q = 0; q < 8; ++q) {
            u64x2 r2 = rp[(base >> 1) + q];
            unsigned long long ra = r2.x, rb = r2.y;
            unsigned fa = (unsigned)ra, fbu = (unsigned)rb;
            key[2*q+0] = (ra & 0xFFFFFFFF00000000ULL) | (unsigned)(base + 2*q+0);
            key[2*q+1] = (rb & 0xFFFFFFFF00000000ULL) | (unsigned)(base + 2*q+1);
            cell[2*q+0] = (unsigned short)(fa & 4095u);
            cell[2*q+1] = (unsigned short)(fbu & 4095u);
            bk[2*q+0] = (unsigned short)(fa >> 12);
            bk[2*q+1] = (unsigned short)(fbu >> 12);
        }
        cnt = 16;
    } else if (base < n) {
        for (int i = base; i < n && i < base + 16; ++i) {
            int j = i - base;
            unsigned long long r = g_recs[i];
            unsigned f = (unsigned)r;
            key[j] = (r & 0xFFFFFFFF00000000ULL) | (unsigned)i;
            cell[j] = (unsigned short)(f & 4095u);
            bk[j] = (unsigned short)(f >> 12);
            ++cnt;
        }
    }
    for (int j = 0; j < cnt; ++j) atomicAdd(&s_cnt[bk[j]], 1u);
    __syncthreads();
    if (tid == 0) {
        unsigned a = 0;
        for (int i = 0; i < kNBk; ++i) { s_scan[i] = a; a += s_cnt[i]; }
    }
    __syncthreads();
    for (int i = tid; i < kNBk; i += 256) {
        unsigned c = s_cnt[i];
        s_lcur[i] = s_scan[i];
        if (c) {
            unsigned pos = atomicAdd(&g_cursor[i << 4], c);
            if (pos + c > (unsigned)((i + 1) * kCap)) {   // overflow (~impossible)
                g_fb = 1;
                s_gbase[i] = 0xFFFFFFFFu;
            } else {
                s_gbase[i] = pos;
            }
        }
    }
    __syncthreads();
    for (int j = 0; j < cnt; ++j) {
        unsigned p = atomicAdd(&s_lcur[bk[j]], 1u);
        s_key[p] = key[j];
        s_cell[p] = cell[j];
    }
    __syncthreads();
    const int w = tid >> 6, lane = tid & 63;
    for (int r = w; r < kNBk; r += 4) {
        unsigned c = s_cnt[r];
        if (!c) continue;
        unsigned gb = s_gbase[r];
        if (gb == 0xFFFFFFFFu) continue;
        unsigned sb = s_scan[r];
        for (unsigned i = lane; i < c; i += 64) {
            g_keyb[gb + i] = s_key[sb + i];
            g_cellb[gb + i] = s_cell[sb + i];
        }
    }
}

// Per-bucket LDS reduction: phase A max(hbits) per cell, phase B min(idx)
// among bit-equal maxers (== ref's two-scatter), winners -> out directly.
__global__ void __launch_bounds__(256) k_reduce(int n, float* __restrict__ out) {
    if (g_fb || !okfast()) return;
    __shared__ unsigned s_hmax[4096], s_imin[4096];
    const int tid = threadIdx.x;
    const int bk = blockIdx.x;
    for (int i = tid; i < 4096; i += 256) { s_hmax[i] = 0u; s_imin[i] = 0xFFFFFFFFu; }
    __syncthreads();
    const unsigned lo = (unsigned)(bk * kCap);
    const unsigned hi = g_cursor[bk << 4];
    for (unsigned i = lo + tid; i < hi; i += 256)
        atomicMax(&s_hmax[g_cellb[i]], (unsigned)(g_keyb[i] >> 32));
    __syncthreads();
    for (unsigned i = lo + tid; i < hi; i += 256) {
        unsigned long long k = g_keyb[i];
        unsigned c = g_cellb[i];
        if ((unsigned)(k >> 32) == s_hmax[c])
            atomicMin(&s_imin[c], (unsigned)k);
    }
    __syncthreads();
    for (int c = tid; c < 4096; c += 256) {
        unsigned im = s_imin[c];
        if (im != 0xFFFFFFFFu) {
            out[im] = __uint_as_float(s_hmax[c]);   // [0,n) kept_heights
            out[n + im] = 1.0f;                     // [n,2n) keep
        }
    }
}

// ---- gated fallback chain (exact R14 logic; runs only if g_fb) ----
__global__ void k_fb_zero() {
    if (!g_fb) return;
    int i = blockIdx.x * blockDim.x + threadIdx.x;
    int stride = gridDim.x * blockDim.x;
    for (int c = i; c < kNumCells; c += stride) g_cell[c] = 0ULL;
}
__global__ void k_fb_scatter(const float* __restrict__ xyz,
                             const int* __restrict__ bidx, int n) {
    if (!g_fb) return;
    int i = blockIdx.x * blockDim.x + threadIdx.x;
    if (i >= n) return;
    const int minr = g_minr, minc = g_minc;
    const int rmax = g_maxr - minr, cmax = g_maxc - minc;
    float x = xyz[3 * i + 0], h = xyz[3 * i + 1], z = xyz[3 * i + 2];
    int qr = quant(z) - minr, qc = quant(x) - minc;
    int flat = bidx[i] * (rmax * cmax) + qr * cmax + qc;
    if (flat >= 0 && flat < kNumCells) {
        unsigned long long key =
            ((unsigned long long)__float_as_uint(h) << 32) | (unsigned)(~i);
        if (key > g_cell[flat]) atomicMax(&g_cell[flat], key);
    }
}
__global__ void k_fb_fin(int n, float* __restrict__ out) {
    if (!g_fb) return;
    int i = blockIdx.x * blockDim.x + threadIdx.x;
    int stride = gridDim.x * blockDim.x;
    for (int c = i; c < kNumCells; c += stride) {
        unsigned long long key = g_cell[c];
        if (key == 0ULL) continue;
        unsigned winner = ~(unsigned)key;
        out[winner] = __uint_as_float((unsigned)(key >> 32));
        out[n + winner] = 1.0f;
    }
}
__global__ void k_reset() {
    if (threadIdx.x == 0) {
        g_fb = 0;
        g_minr = INT_MAX; g_maxr = INT_MIN;
        g_minc = INT_MAX; g_maxc = INT_MIN;
    }
}

extern "C" void kernel_launch(void* const* d_in, const int* in_sizes, int n_in,
                              void* d_out, int out_size, void* d_ws, size_t ws_size,
                              hipStream_t stream) {
    const float* xyz = (const float*)d_in[0];
    const int* bidx = (const int*)d_in[1];
    // d_in[2] (semantics) unused by the reference.
    int n = in_sizes[1];

    const int B = 256;
    int gridPart = (n + 4095) >> 12;            // 2048
    int gridFb = (n + B - 1) / B;               // fb scatter grid
    k_prep<<<4096, B, 0, stream>>>(xyz, bidx, n, (float*)d_out, out_size, 1024);
    k_cursor<<<(kNBk + B - 1) / B, B, 0, stream>>>();
    k_part<<<gridPart, B, 0, stream>>>(n);
    k_reduce<<<kNBk, B, 0, stream>>>(n, (float*)d_out);
    k_fb_zero<<<2048, B, 0, stream>>>();
    k_fb_scatter<<<gridFb, B, 0, stream>>>(xyz, bidx, n);
    k_fb_fin<<<2048, B, 0, stream>>>(n, (float*)d_out);
    k_reset<<<1, 64, 0, stream>>>();
}

// Round 23
// 318.698 us; speedup vs baseline: 1.9751x; 1.5780x over previous
//
#include <hip/hip_runtime.h>
#include <climits>

// R23: single fused pass (zero-out ∥ partition-from-xyz ∥ minmax), rank-trick
// (count atomicAdd returns rank), parallel prefix scan. No records, no global
// atomics in the hot path. Fast-path flat assumes minr=minc=0,maxr=maxc=800
// (verified post-hoc; gated R14-style fallback otherwise).
static constexpr int kN = 8388608;
static constexpr int kNumCells = 3216822;     // fallback cell array
static constexpr int kMaxFlat = 2560800;      // 3*640000 + 800*800 + 800
static constexpr int kNBk = (kMaxFlat >> 12) + 1;   // 626 buckets x 4096 cells
static constexpr int kCap = 16384;            // per-bucket capacity (~22% slack)

typedef float __attribute__((ext_vector_type(4))) f32x4;
typedef int   __attribute__((ext_vector_type(4))) i32x4;

__device__ __align__(16) unsigned long long g_keyb[(unsigned)kNBk * kCap]; // hbits<<32|idx
__device__ __align__(16) unsigned short g_cellb[(unsigned)kNBk * kCap];    // flat & 4095
__device__ unsigned g_cursor[kNBk * 16];      // 64B-padded cursors
__device__ unsigned long long g_cell[kNumCells];   // fallback path only
__device__ int g_minr = INT_MAX, g_maxr = INT_MIN;
__device__ int g_minc = INT_MAX, g_maxc = INT_MIN;
__device__ int g_fb = 0;

__device__ __forceinline__ int quant(float v) {
    return (int)rintf(v * 40.0f);   // np-ref rule (proven R11/R12)
}
__device__ __forceinline__ bool okfast() {
    return g_minr == 0 && g_maxr == 800 && g_minc == 0 && g_maxc == 800;
}

__global__ void k_cursor() {
    int i = blockIdx.x * blockDim.x + threadIdx.x;
    if (i < kNBk) g_cursor[i << 4] = (unsigned)(i * kCap);
}

// Fused: blocks [0,zb) zero out[]; blocks [zb,..) partition their 4096-pt
// chunk directly from xyz (strided 4-pt groups => coalesced loads), and
// accumulate the minmax used by the okfast gate / fallback.
__global__ void __launch_bounds__(256) k_main(const float* __restrict__ xyz,
                                              const int* __restrict__ bidx, int n,
                                              float* __restrict__ out, int total,
                                              int zb) {
    const int tid = threadIdx.x;
    if (blockIdx.x < zb) {
        int t = blockIdx.x * blockDim.x + tid;
        int S = zb * blockDim.x;
        float4 f4 = make_float4(0.f, 0.f, 0.f, 0.f);
        float4* o4 = (float4*)out;
        const int no4 = total >> 2;
        for (int i = t; i < no4; i += S) o4[i] = f4;
        for (int i = (no4 << 2) + t; i < total; i += S) out[i] = 0.f;
        return;
    }
    const int chunk0 = (blockIdx.x - zb) << 12;
    if (chunk0 >= n) return;

    __shared__ unsigned s_cnt[kNBk], s_scan[kNBk], s_gbase[kNBk];
    __shared__ unsigned s_wsum[4];
    __shared__ int s_mm[4][4];
    __shared__ unsigned long long s_key[4096];
    __shared__ unsigned short s_cell[4096];
    for (int i = tid; i < kNBk; i += 256) s_cnt[i] = 0;
    __syncthreads();

    unsigned long long key[16];
    unsigned short cell[16], bkt[16], rank[16];
    int mnr = INT_MAX, mxr = INT_MIN, mnc = INT_MAX, mxc = INT_MIN;
    int cnt = 0;
    const f32x4* p = (const f32x4*)xyz;
    const i32x4* bp = (const i32x4*)bidx;
#pragma unroll
    for (int k = 0; k < 4; ++k) {
        int gidx = (chunk0 >> 2) + k * 256 + tid;   // 4-pt group, wave-coalesced
        int base = gidx << 2;
        if (base >= n) break;
        if (base + 3 < n) {
            f32x4 f0 = p[3 * gidx + 0];   // x0 h0 z0 x1
            f32x4 f1 = p[3 * gidx + 1];   // h1 z1 x2 h2
            f32x4 f2 = p[3 * gidx + 2];   // z2 x3 h3 z3
            i32x4 b4 = bp[gidx];
            float xs[4] = {f0.x, f0.w, f1.z, f2.y};
            float hs[4] = {f0.y, f1.x, f1.w, f2.z};
            float zs[4] = {f0.z, f1.y, f2.x, f2.w};
            int bs[4] = {b4.x, b4.y, b4.z, b4.w};
#pragma unroll
            for (int j = 0; j < 4; ++j) {
                int qr = quant(zs[j]);
                int qc = quant(xs[j]);
                mnr = min(mnr, qr); mxr = max(mxr, qr);
                mnc = min(mnc, qc); mxc = max(mxc, qc);
                long long fl = (long long)bs[j] * 640000 + (long long)qr * 800 + qc;
                unsigned flu = (unsigned)min(max(fl, 0LL), (long long)kMaxFlat);
                key[cnt] = ((unsigned long long)__float_as_uint(hs[j]) << 32)
                         | (unsigned)(base + j);
                cell[cnt] = (unsigned short)(flu & 4095u);
                unsigned bb = flu >> 12;
                bkt[cnt] = (unsigned short)bb;
                rank[cnt] = (unsigned short)atomicAdd(&s_cnt[bb], 1u);
                ++cnt;
            }
        } else {
            for (int i = base; i < n && i < base + 4; ++i) {
                float x = xyz[3 * i + 0], h = xyz[3 * i + 1], z = xyz[3 * i + 2];
                int qr = quant(z), qc = quant(x);
                mnr = min(mnr, qr); mxr = max(mxr, qr);
                mnc = min(mnc, qc); mxc = max(mxc, qc);
                long long fl = (long long)bidx[i] * 640000 + (long long)qr * 800 + qc;
                unsigned flu = (unsigned)min(max(fl, 0LL), (long long)kMaxFlat);
                key[cnt] = ((unsigned long long)__float_as_uint(h) << 32) | (unsigned)i;
                cell[cnt] = (unsigned short)(flu & 4095u);
                unsigned bb = flu >> 12;
                bkt[cnt] = (unsigned short)bb;
                rank[cnt] = (unsigned short)atomicAdd(&s_cnt[bb], 1u);
                ++cnt;
            }
        }
    }
    // minmax block-reduce (for okfast gate + fallback geometry)
#pragma unroll
    for (int off = 32; off > 0; off >>= 1) {
        mnr = min(mnr, __shfl_down(mnr, off));
        mxr = max(mxr, __shfl_down(mxr, off));
        mnc = min(mnc, __shfl_down(mnc, off));
        mxc = max(mxc, __shfl_down(mxc, off));
    }
    const int w = tid >> 6, lane = tid & 63;
    if (lane == 0) {
        s_mm[w][0] = mnr; s_mm[w][1] = mxr; s_mm[w][2] = mnc; s_mm[w][3] = mxc;
    }
    __syncthreads();   // counts final + minmax partials in LDS
    if (tid == 0) {
        atomicMin(&g_minr, min(min(s_mm[0][0], s_mm[1][0]), min(s_mm[2][0], s_mm[3][0])));
        atomicMax(&g_maxr, max(max(s_mm[0][1], s_mm[1][1]), max(s_mm[2][1], s_mm[3][1])));
        atomicMin(&g_minc, min(min(s_mm[0][2], s_mm[1][2]), min(s_mm[2][2], s_mm[3][2])));
        atomicMax(&g_maxc, max(max(s_mm[0][3], s_mm[1][3]), max(s_mm[2][3], s_mm[3][3])));
    }
    // parallel exclusive scan of s_cnt[0..626) -> s_scan
    int e0 = tid * 3;
    unsigned l0 = (e0 + 0 < kNBk) ? s_cnt[e0 + 0] : 0u;
    unsigned l1 = (e0 + 1 < kNBk) ? s_cnt[e0 + 1] : 0u;
    unsigned l2 = (e0 + 2 < kNBk) ? s_cnt[e0 + 2] : 0u;
    unsigned tsum = l0 + l1 + l2;
    unsigned inc = tsum;
#pragma unroll
    for (int off = 1; off < 64; off <<= 1) {
        unsigned v = __shfl_up(inc, off);
        if (lane >= off) inc += v;
    }
    if (lane == 63) s_wsum[w] = inc;
    __syncthreads();
    if (tid == 0) {
        unsigned a = 0;
#pragma unroll
        for (int i = 0; i < 4; ++i) { unsigned t = s_wsum[i]; s_wsum[i] = a; a += t; }
    }
    __syncthreads();
    unsigned excl = inc - tsum + s_wsum[w];
    if (e0 + 0 < kNBk) s_scan[e0 + 0] = excl;
    if (e0 + 1 < kNBk) s_scan[e0 + 1] = excl + l0;
    if (e0 + 2 < kNBk) s_scan[e0 + 2] = excl + l0 + l1;
    __syncthreads();
    // cursor reservation (one padded-line atomic per nonempty bucket)
    for (int i = tid; i < kNBk; i += 256) {
        unsigned c = s_cnt[i];
        if (c) {
            unsigned pos = atomicAdd(&g_cursor[i << 4], c);
            if (pos + c > (unsigned)((i + 1) * kCap)) { g_fb = 1; s_gbase[i] = 0xFFFFFFFFu; }
            else s_gbase[i] = pos;
        }
    }
    // stage into LDS at scan+rank positions
    for (int j = 0; j < cnt; ++j) {
        unsigned pos = s_scan[bkt[j]] + rank[j];
        s_key[pos] = key[j];
        s_cell[pos] = cell[j];
    }
    __syncthreads();
    // coalesced copy-out per bucket run
    for (int r = w; r < kNBk; r += 4) {
        unsigned c = s_cnt[r];
        if (!c) continue;
        unsigned gb = s_gbase[r];
        if (gb == 0xFFFFFFFFu) continue;
        unsigned sb = s_scan[r];
        for (unsigned i = lane; i < c; i += 64) {
            g_keyb[gb + i] = s_key[sb + i];
            g_cellb[gb + i] = s_cell[sb + i];
        }
    }
}

__global__ void k_gate() {
    if (threadIdx.x == 0 && blockIdx.x == 0) {
        if (!okfast()) g_fb = 1;
    }
}

// Per-bucket LDS reduce: max hbits per cell, then min idx among bit-equal
// maxers (== ref's two-scatter). Winners straight to out (pre-zeroed).
__global__ void __launch_bounds__(256) k_reduce(int n, float* __restrict__ out) {
    if (g_fb) return;
    __shared__ unsigned s_hmax[4096], s_imin[4096];
    const int tid = threadIdx.x;
    const int bk = blockIdx.x;
    for (int i = tid; i < 4096; i += 256) { s_hmax[i] = 0u; s_imin[i] = 0xFFFFFFFFu; }
    __syncthreads();
    const unsigned lo = (unsigned)(bk * kCap);
    unsigned hi = g_cursor[bk << 4];
    const unsigned cap = (unsigned)((bk + 1) * kCap);
    if (hi > cap) hi = cap;
    for (unsigned i = lo + tid; i < hi; i += 256)
        atomicMax(&s_hmax[g_cellb[i]], (unsigned)(g_keyb[i] >> 32));
    __syncthreads();
    for (unsigned i = lo + tid; i < hi; i += 256) {
        unsigned long long k = g_keyb[i];
        unsigned c = g_cellb[i];
        if ((unsigned)(k >> 32) == s_hmax[c])
            atomicMin(&s_imin[c], (unsigned)k);
    }
    __syncthreads();
    for (int c = tid; c < 4096; c += 256) {
        unsigned im = s_imin[c];
        if (im != 0xFFFFFFFFu) {
            out[im] = __uint_as_float(s_hmax[c]);   // [0,n) kept_heights
            out[n + im] = 1.0f;                     // [n,2n) keep
        }
    }
}

// ---- gated fallback chain (exact R14 logic; runs only if g_fb) ----
__global__ void k_fb_zero() {
    if (!g_fb) return;
    int i = blockIdx.x * blockDim.x + threadIdx.x;
    int stride = gridDim.x * blockDim.x;
    for (int c = i; c < kNumCells; c += stride) g_cell[c] = 0ULL;
}
__global__ void k_fb_scatter(const float* __restrict__ xyz,
                             const int* __restrict__ bidx, int n) {
    if (!g_fb) return;
    const int minr = g_minr, minc = g_minc;
    const int rmax = g_maxr - minr, cmax = g_maxc - minc;
    int t = blockIdx.x * blockDim.x + threadIdx.x;
    int S = gridDim.x * blockDim.x;
    for (int i = t; i < n; i += S) {
        float x = xyz[3 * i + 0], h = xyz[3 * i + 1], z = xyz[3 * i + 2];
        int qr = quant(z) - minr, qc = quant(x) - minc;
        int flat = bidx[i] * (rmax * cmax) + qr * cmax + qc;
        if (flat >= 0 && flat < kNumCells) {
            unsigned long long key =
                ((unsigned long long)__float_as_uint(h) << 32) | (unsigned)(~i);
            if (key > g_cell[flat]) atomicMax(&g_cell[flat], key);
        }
    }
}
__global__ void k_fb_fin(int n, float* __restrict__ out) {
    if (!g_fb) return;
    int i = blockIdx.x * blockDim.x + threadIdx.x;
    int stride = gridDim.x * blockDim.x;
    for (int c = i; c < kNumCells; c += stride) {
        unsigned long long key = g_cell[c];
        if (key == 0ULL) continue;
        unsigned winner = ~(unsigned)key;
        out[winner] = __uint_as_float((unsigned)(key >> 32));
        out[n + winner] = 1.0f;
    }
}
__global__ void k_reset() {
    if (threadIdx.x == 0 && blockIdx.x == 0) {
        g_fb = 0;
        g_minr = INT_MAX; g_maxr = INT_MIN;
        g_minc = INT_MAX; g_maxc = INT_MIN;
    }
}

extern "C" void kernel_launch(void* const* d_in, const int* in_sizes, int n_in,
                              void* d_out, int out_size, void* d_ws, size_t ws_size,
                              hipStream_t stream) {
    const float* xyz = (const float*)d_in[0];
    const int* bidx = (const int*)d_in[1];
    // d_in[2] (semantics) unused by the reference.
    int n = in_sizes[1];

    const int B = 256;
    const int zb = 512;
    int gridMain = zb + ((n + 4095) >> 12);     // 512 + 2048
    k_cursor<<<(kNBk + B - 1) / B, B, 0, stream>>>();
    k_main<<<gridMain, B, 0, stream>>>(xyz, bidx, n, (float*)d_out, out_size, zb);
    k_gate<<<1, 64, 0, stream>>>();
    k_reduce<<<kNBk, B, 0, stream>>>(n, (float*)d_out);
    k_fb_zero<<<2048, B, 0, stream>>>();
    k_fb_scatter<<<4096, B, 0, stream>>>(xyz, bidx, n);
    k_fb_fin<<<2048, B, 0, stream>>>(n, (float*)d_out);
    k_reset<<<1, 64, 0, stream>>>();
}

// Round 24
// 308.538 us; speedup vs baseline: 2.0402x; 1.0329x over previous
//
#include <hip/hip_runtime.h>
#include <climits>

// R24: registerize k_main's per-point state. R23's key[16]/rank[16] etc. were
// runtime-indexed (dynamic cnt) -> compiler spilled to scratch (VGPR=68!).
// Now: literal-bound unrolled loops + valid flags; arrays stay in VGPRs.
static constexpr int kN = 8388608;
static constexpr int kNumCells = 3216822;     // fallback cell array
static constexpr int kMaxFlat = 2560800;      // 3*640000 + 800*800 + 800
static constexpr int kNBk = (kMaxFlat >> 12) + 1;   // 626 buckets x 4096 cells
static constexpr int kCap = 16384;            // per-bucket capacity (~22% slack)

typedef float __attribute__((ext_vector_type(4))) f32x4;
typedef int   __attribute__((ext_vector_type(4))) i32x4;

__device__ __align__(16) unsigned long long g_keyb[(unsigned)kNBk * kCap]; // hbits<<32|idx
__device__ __align__(16) unsigned short g_cellb[(unsigned)kNBk * kCap];    // flat & 4095
__device__ unsigned g_cursor[kNBk * 16];      // 64B-padded cursors
__device__ unsigned long long g_cell[kNumCells];   // fallback path only
__device__ int g_minr = INT_MAX, g_maxr = INT_MIN;
__device__ int g_minc = INT_MAX, g_maxc = INT_MIN;
__device__ int g_fb = 0;

__device__ __forceinline__ int quant(float v) {
    return (int)rintf(v * 40.0f);   // np-ref rule (proven R11/R12)
}
__device__ __forceinline__ bool okfast() {
    return g_minr == 0 && g_maxr == 800 && g_minc == 0 && g_maxc == 800;
}

__global__ void k_cursor() {
    int i = blockIdx.x * blockDim.x + threadIdx.x;
    if (i < kNBk) g_cursor[i << 4] = (unsigned)(i * kCap);
}

// Fused: blocks [0,zb) zero out[]; blocks [zb,..) partition their 4096-pt
// chunk from xyz. ALL per-point arrays constant-indexed => VGPR-resident.
__global__ void __launch_bounds__(256) k_main(const float* __restrict__ xyz,
                                              const int* __restrict__ bidx, int n,
                                              float* __restrict__ out, int total,
                                              int zb) {
    const int tid = threadIdx.x;
    if (blockIdx.x < zb) {
        int t = blockIdx.x * blockDim.x + tid;
        int S = zb * blockDim.x;
        float4 f4 = make_float4(0.f, 0.f, 0.f, 0.f);
        float4* o4 = (float4*)out;
        const int no4 = total >> 2;
        for (int i = t; i < no4; i += S) o4[i] = f4;
        for (int i = (no4 << 2) + t; i < total; i += S) out[i] = 0.f;
        return;
    }
    const int chunk0 = (blockIdx.x - zb) << 12;
    if (chunk0 >= n) return;

    __shared__ unsigned s_cnt[kNBk], s_scan[kNBk], s_gbase[kNBk];
    __shared__ unsigned s_wsum[4];
    __shared__ int s_mm[4][4];
    __shared__ unsigned long long s_key[4096];
    __shared__ unsigned short s_cell[4096];
    for (int i = tid; i < kNBk; i += 256) s_cnt[i] = 0;
    __syncthreads();

    // --- per-point state, ALL constant-indexed (VGPR-resident) ---
    unsigned hb[16], flu[16], rank[16];
    bool val[16];
    int mnr = INT_MAX, mxr = INT_MIN, mnc = INT_MAX, mxc = INT_MIN;
    const f32x4* p = (const f32x4*)xyz;
    const i32x4* bp = (const i32x4*)bidx;
    const int g0 = (chunk0 >> 2) + tid;     // 4-pt group id, +k*256 per round
#pragma unroll
    for (int k = 0; k < 4; ++k) {
        const int gidx = g0 + (k << 8);
        const int pbase = gidx << 2;
        float xs[4], hs[4], zs[4]; int bs[4];
        if (pbase + 3 < n) {
            f32x4 f0 = p[3 * gidx + 0];   // x0 h0 z0 x1
            f32x4 f1 = p[3 * gidx + 1];   // h1 z1 x2 h2
            f32x4 f2 = p[3 * gidx + 2];   // z2 x3 h3 z3
            i32x4 b4 = bp[gidx];
            xs[0]=f0.x; hs[0]=f0.y; zs[0]=f0.z;
            xs[1]=f0.w; hs[1]=f1.x; zs[1]=f1.y;
            xs[2]=f1.z; hs[2]=f1.w; zs[2]=f2.x;
            xs[3]=f2.y; hs[3]=f2.z; zs[3]=f2.w;
            bs[0]=b4.x; bs[1]=b4.y; bs[2]=b4.z; bs[3]=b4.w;
        } else {
#pragma unroll
            for (int j = 0; j < 4; ++j) {
                int i = pbase + j;
                bool v = i < n;
                xs[j] = v ? xyz[3 * i + 0] : 0.f;
                hs[j] = v ? xyz[3 * i + 1] : 0.f;
                zs[j] = v ? xyz[3 * i + 2] : 0.f;
                bs[j] = v ? bidx[i] : 0;
            }
        }
#pragma unroll
        for (int j = 0; j < 4; ++j) {
            const int e = (k << 2) + j;           // constant index
            bool v = (pbase + j) < n;
            val[e] = v;
            int qr = quant(zs[j]);
            int qc = quant(xs[j]);
            if (v) {
                mnr = min(mnr, qr); mxr = max(mxr, qr);
                mnc = min(mnc, qc); mxc = max(mxc, qc);
            }
            long long fl = (long long)bs[j] * 640000 + (long long)qr * 800 + qc;
            unsigned f = (unsigned)min(max(fl, 0LL), (long long)kMaxFlat);
            flu[e] = f;
            hb[e] = __float_as_uint(hs[j]);
            rank[e] = v ? (unsigned)atomicAdd(&s_cnt[f >> 12], 1u) : 0u;
        }
    }
    // minmax block-reduce (okfast gate + fallback geometry)
#pragma unroll
    for (int off = 32; off > 0; off >>= 1) {
        mnr = min(mnr, __shfl_down(mnr, off));
        mxr = max(mxr, __shfl_down(mxr, off));
        mnc = min(mnc, __shfl_down(mnc, off));
        mxc = max(mxc, __shfl_down(mxc, off));
    }
    const int w = tid >> 6, lane = tid & 63;
    if (lane == 0) {
        s_mm[w][0] = mnr; s_mm[w][1] = mxr; s_mm[w][2] = mnc; s_mm[w][3] = mxc;
    }
    __syncthreads();   // counts final + minmax partials
    if (tid == 0) {
        atomicMin(&g_minr, min(min(s_mm[0][0], s_mm[1][0]), min(s_mm[2][0], s_mm[3][0])));
        atomicMax(&g_maxr, max(max(s_mm[0][1], s_mm[1][1]), max(s_mm[2][1], s_mm[3][1])));
        atomicMin(&g_minc, min(min(s_mm[0][2], s_mm[1][2]), min(s_mm[2][2], s_mm[3][2])));
        atomicMax(&g_maxc, max(max(s_mm[0][3], s_mm[1][3]), max(s_mm[2][3], s_mm[3][3])));
    }
    // parallel exclusive scan of s_cnt[0..626) -> s_scan
    int e0 = tid * 3;
    unsigned l0 = (e0 + 0 < kNBk) ? s_cnt[e0 + 0] : 0u;
    unsigned l1 = (e0 + 1 < kNBk) ? s_cnt[e0 + 1] : 0u;
    unsigned l2 = (e0 + 2 < kNBk) ? s_cnt[e0 + 2] : 0u;
    unsigned tsum = l0 + l1 + l2;
    unsigned inc = tsum;
#pragma unroll
    for (int off = 1; off < 64; off <<= 1) {
        unsigned v = __shfl_up(inc, off);
        if (lane >= off) inc += v;
    }
    if (lane == 63) s_wsum[w] = inc;
    __syncthreads();
    if (tid == 0) {
        unsigned a = 0;
#pragma unroll
        for (int i = 0; i < 4; ++i) { unsigned t = s_wsum[i]; s_wsum[i] = a; a += t; }
    }
    __syncthreads();
    unsigned excl = inc - tsum + s_wsum[w];
    if (e0 + 0 < kNBk) s_scan[e0 + 0] = excl;
    if (e0 + 1 < kNBk) s_scan[e0 + 1] = excl + l0;
    if (e0 + 2 < kNBk) s_scan[e0 + 2] = excl + l0 + l1;
    __syncthreads();
    // cursor reservation (one padded-line atomic per nonempty bucket)
    for (int i = tid; i < kNBk; i += 256) {
        unsigned c = s_cnt[i];
        if (c) {
            unsigned pos = atomicAdd(&g_cursor[i << 4], c);
            if (pos + c > (unsigned)((i + 1) * kCap)) { g_fb = 1; s_gbase[i] = 0xFFFFFFFFu; }
            else s_gbase[i] = pos;
        }
    }
    // stage into LDS at scan+rank positions (constant-indexed reg reads)
#pragma unroll
    for (int e = 0; e < 16; ++e) {
        if (val[e]) {
            const int k = e >> 2, j = e & 3;
            unsigned idx = (unsigned)(((g0 + (k << 8)) << 2) + j);
            unsigned pos = s_scan[flu[e] >> 12] + rank[e];
            s_key[pos] = ((unsigned long long)hb[e] << 32) | idx;
            s_cell[pos] = (unsigned short)(flu[e] & 4095u);
        }
    }
    __syncthreads();
    // coalesced copy-out per bucket run
    for (int r = w; r < kNBk; r += 4) {
        unsigned c = s_cnt[r];
        if (!c) continue;
        unsigned gb = s_gbase[r];
        if (gb == 0xFFFFFFFFu) continue;
        unsigned sb = s_scan[r];
        for (unsigned i = lane; i < c; i += 64) {
            g_keyb[gb + i] = s_key[sb + i];
            g_cellb[gb + i] = s_cell[sb + i];
        }
    }
}

__global__ void k_gate() {
    if (threadIdx.x == 0 && blockIdx.x == 0) {
        if (!okfast()) g_fb = 1;
    }
}

// Per-bucket LDS reduce: max hbits per cell, then min idx among bit-equal
// maxers (== ref's two-scatter). Winners straight to out (pre-zeroed).
__global__ void __launch_bounds__(256) k_reduce(int n, float* __restrict__ out) {
    if (g_fb) return;
    __shared__ unsigned s_hmax[4096], s_imin[4096];
    const int tid = threadIdx.x;
    const int bk = blockIdx.x;
    for (int i = tid; i < 4096; i += 256) { s_hmax[i] = 0u; s_imin[i] = 0xFFFFFFFFu; }
    __syncthreads();
    const unsigned lo = (unsigned)(bk * kCap);
    unsigned hi = g_cursor[bk << 4];
    const unsigned cap = (unsigned)((bk + 1) * kCap);
    if (hi > cap) hi = cap;
    for (unsigned i = lo + tid; i < hi; i += 256)
        atomicMax(&s_hmax[g_cellb[i]], (unsigned)(g_keyb[i] >> 32));
    __syncthreads();
    for (unsigned i = lo + tid; i < hi; i += 256) {
        unsigned long long k = g_keyb[i];
        unsigned c = g_cellb[i];
        if ((unsigned)(k >> 32) == s_hmax[c])
            atomicMin(&s_imin[c], (unsigned)k);
    }
    __syncthreads();
    for (int c = tid; c < 4096; c += 256) {
        unsigned im = s_imin[c];
        if (im != 0xFFFFFFFFu) {
            out[im] = __uint_as_float(s_hmax[c]);   // [0,n) kept_heights
            out[n + im] = 1.0f;                     // [n,2n) keep
        }
    }
}

// ---- gated fallback chain (exact R14 logic; runs only if g_fb) ----
__global__ void k_fb_zero() {
    if (!g_fb) return;
    int i = blockIdx.x * blockDim.x + threadIdx.x;
    int stride = gridDim.x * blockDim.x;
    for (int c = i; c < kNumCells; c += stride) g_cell[c] = 0ULL;
}
__global__ void k_fb_scatter(const float* __restrict__ xyz,
                             const int* __restrict__ bidx, int n) {
    if (!g_fb) return;
    const int minr = g_minr, minc = g_minc;
    const int rmax = g_maxr - minr, cmax = g_maxc - minc;
    int t = blockIdx.x * blockDim.x + threadIdx.x;
    int S = gridDim.x * blockDim.x;
    for (int i = t; i < n; i += S) {
        float x = xyz[3 * i + 0], h = xyz[3 * i + 1], z = xyz[3 * i + 2];
        int qr = quant(z) - minr, qc = quant(x) - minc;
        int flat = bidx[i] * (rmax * cmax) + qr * cmax + qc;
        if (flat >= 0 && flat < kNumCells) {
            unsigned long long key =
                ((unsigned long long)__float_as_uint(h) << 32) | (unsigned)(~i);
            if (key > g_cell[flat]) atomicMax(&g_cell[flat], key);
        }
    }
}
__global__ void k_fb_fin(int n, float* __restrict__ out) {
    if (!g_fb) return;
    int i = blockIdx.x * blockDim.x + threadIdx.x;
    int stride = gridDim.x * blockDim.x;
    for (int c = i; c < kNumCells; c += stride) {
        unsigned long long key = g_cell[c];
        if (key == 0ULL) continue;
        unsigned winner = ~(unsigned)key;
        out[winner] = __uint_as_float((unsigned)(key >> 32));
        out[n + winner] = 1.0f;
    }
}
__global__ void k_reset() {
    if (threadIdx.x == 0 && blockIdx.x == 0) {
        g_fb = 0;
        g_minr = INT_MAX; g_maxr = INT_MIN;
        g_minc = INT_MAX; g_maxc = INT_MIN;
    }
}

extern "C" void kernel_launch(void* const* d_in, const int* in_sizes, int n_in,
                              void* d_out, int out_size, void* d_ws, size_t ws_size,
                              hipStream_t stream) {
    const float* xyz = (const float*)d_in[0];
    const int* bidx = (const int*)d_in[1];
    // d_in[2] (semantics) unused by the reference.
    int n = in_sizes[1];

    const int B = 256;
    const int zb = 512;
    int gridMain = zb + ((n + 4095) >> 12);     // 512 + 2048
    k_cursor<<<(kNBk + B - 1) / B, B, 0, stream>>>();
    k_main<<<gridMain, B, 0, stream>>>(xyz, bidx, n, (float*)d_out, out_size, zb);
    k_gate<<<1, 64, 0, stream>>>();
    k_reduce<<<kNBk, B, 0, stream>>>(n, (float*)d_out);
    k_fb_zero<<<2048, B, 0, stream>>>();
    k_fb_scatter<<<4096, B, 0, stream>>>(xyz, bidx, n);
    k_fb_fin<<<2048, B, 0, stream>>>(n, (float*)d_out);
    k_reset<<<1, 64, 0, stream>>>();
}

// Round 25
// 306.551 us; speedup vs baseline: 2.0534x; 1.0065x over previous
//
#include <hip/hip_runtime.h>
#include <climits>

// R25: delete LDS staging/scan/copy-out. Histogram rank -> cursor reservation
// -> DIRECT global writes (same line pattern as the old copy-out, but no
// 40KB LDS => occupancy 30%->~87%). Fast path assumes minr=minc=0,
// maxr=maxc=800 (verified; gated fallback otherwise).
static constexpr int kN = 8388608;
static constexpr int kNumCells = 3216822;     // fallback cell array
static constexpr int kMaxFlat = 2560800;      // 3*640000 + 800*800 + 800
static constexpr int kNBk = (kMaxFlat >> 12) + 1;   // 626 buckets x 4096 cells
static constexpr int kCap = 16384;            // per-bucket capacity (~22% slack)

typedef float __attribute__((ext_vector_type(4))) f32x4;
typedef int   __attribute__((ext_vector_type(4))) i32x4;

__device__ __align__(16) unsigned long long g_keyb[(unsigned)kNBk * kCap]; // hbits<<32|idx
__device__ __align__(16) unsigned short g_cellb[(unsigned)kNBk * kCap];    // flat & 4095
__device__ unsigned g_cursor[kNBk * 16];      // 64B-padded cursors
__device__ unsigned long long g_cell[kNumCells];   // fallback path only
__device__ int g_minr = INT_MAX, g_maxr = INT_MIN;
__device__ int g_minc = INT_MAX, g_maxc = INT_MIN;
__device__ int g_fb = 0;

__device__ __forceinline__ int quant(float v) {
    return (int)rintf(v * 40.0f);   // np-ref rule (proven R11/R12)
}
__device__ __forceinline__ bool okfast() {
    return g_minr == 0 && g_maxr == 800 && g_minc == 0 && g_maxc == 800;
}

__global__ void k_cursor() {
    int i = blockIdx.x * blockDim.x + threadIdx.x;
    if (i < kNBk) g_cursor[i << 4] = (unsigned)(i * kCap);
}

// Fused: blocks [0,zb) zero out[]; blocks [zb,..) partition 4096-pt chunks.
// Phases: load+hist(rank) -> sync -> reserve -> sync -> direct global write.
__global__ void __launch_bounds__(256) k_main(const float* __restrict__ xyz,
                                              const int* __restrict__ bidx, int n,
                                              float* __restrict__ out, int total,
                                              int zb) {
    const int tid = threadIdx.x;
    if (blockIdx.x < zb) {
        int t = blockIdx.x * blockDim.x + tid;
        int S = zb * blockDim.x;
        float4 f4 = make_float4(0.f, 0.f, 0.f, 0.f);
        float4* o4 = (float4*)out;
        const int no4 = total >> 2;
        for (int i = t; i < no4; i += S) o4[i] = f4;
        for (int i = (no4 << 2) + t; i < total; i += S) out[i] = 0.f;
        return;
    }
    const int chunk0 = (blockIdx.x - zb) << 12;
    if (chunk0 >= n) return;

    __shared__ unsigned s_cnt[kNBk], s_gbase[kNBk];
    __shared__ int s_mm[4][4];
    for (int i = tid; i < kNBk; i += 256) s_cnt[i] = 0;
    __syncthreads();

    // --- per-point state, constant-indexed (VGPR-resident) ---
    unsigned hb[16], flu[16], rank[16];
    bool val[16];
    int mnr = INT_MAX, mxr = INT_MIN, mnc = INT_MAX, mxc = INT_MIN;
    const f32x4* p = (const f32x4*)xyz;
    const i32x4* bp = (const i32x4*)bidx;
    const int g0 = (chunk0 >> 2) + tid;     // 4-pt group id, +k*256 per round
#pragma unroll
    for (int k = 0; k < 4; ++k) {
        const int gidx = g0 + (k << 8);
        const int pbase = gidx << 2;
        float xs[4], hs[4], zs[4]; int bs[4];
        if (pbase + 3 < n) {
            f32x4 f0 = p[3 * gidx + 0];   // x0 h0 z0 x1
            f32x4 f1 = p[3 * gidx + 1];   // h1 z1 x2 h2
            f32x4 f2 = p[3 * gidx + 2];   // z2 x3 h3 z3
            i32x4 b4 = bp[gidx];
            xs[0]=f0.x; hs[0]=f0.y; zs[0]=f0.z;
            xs[1]=f0.w; hs[1]=f1.x; zs[1]=f1.y;
            xs[2]=f1.z; hs[2]=f1.w; zs[2]=f2.x;
            xs[3]=f2.y; hs[3]=f2.z; zs[3]=f2.w;
            bs[0]=b4.x; bs[1]=b4.y; bs[2]=b4.z; bs[3]=b4.w;
        } else {
#pragma unroll
            for (int j = 0; j < 4; ++j) {
                int i = pbase + j;
                bool v = i < n;
                xs[j] = v ? xyz[3 * i + 0] : 0.f;
                hs[j] = v ? xyz[3 * i + 1] : 0.f;
                zs[j] = v ? xyz[3 * i + 2] : 0.f;
                bs[j] = v ? bidx[i] : 0;
            }
        }
#pragma unroll
        for (int j = 0; j < 4; ++j) {
            const int e = (k << 2) + j;           // constant index
            bool v = (pbase + j) < n;
            val[e] = v;
            int qr = quant(zs[j]);
            int qc = quant(xs[j]);
            if (v) {
                mnr = min(mnr, qr); mxr = max(mxr, qr);
                mnc = min(mnc, qc); mxc = max(mxc, qc);
            }
            long long fl = (long long)bs[j] * 640000 + (long long)qr * 800 + qc;
            unsigned f = (unsigned)min(max(fl, 0LL), (long long)kMaxFlat);
            flu[e] = f;
            hb[e] = __float_as_uint(hs[j]);
            rank[e] = v ? (unsigned)atomicAdd(&s_cnt[f >> 12], 1u) : 0u;
        }
    }
    // minmax block-reduce (okfast gate + fallback geometry)
#pragma unroll
    for (int off = 32; off > 0; off >>= 1) {
        mnr = min(mnr, __shfl_down(mnr, off));
        mxr = max(mxr, __shfl_down(mxr, off));
        mnc = min(mnc, __shfl_down(mnc, off));
        mxc = max(mxc, __shfl_down(mxc, off));
    }
    const int w = tid >> 6, lane = tid & 63;
    if (lane == 0) {
        s_mm[w][0] = mnr; s_mm[w][1] = mxr; s_mm[w][2] = mnc; s_mm[w][3] = mxc;
    }
    __syncthreads();   // counts final + minmax partials
    if (tid == 0) {
        atomicMin(&g_minr, min(min(s_mm[0][0], s_mm[1][0]), min(s_mm[2][0], s_mm[3][0])));
        atomicMax(&g_maxr, max(max(s_mm[0][1], s_mm[1][1]), max(s_mm[2][1], s_mm[3][1])));
        atomicMin(&g_minc, min(min(s_mm[0][2], s_mm[1][2]), min(s_mm[2][2], s_mm[3][2])));
        atomicMax(&g_maxc, max(max(s_mm[0][3], s_mm[1][3]), max(s_mm[2][3], s_mm[3][3])));
    }
    // cursor reservation (one padded-line atomic per nonempty bucket)
    for (int i = tid; i < kNBk; i += 256) {
        unsigned c = s_cnt[i];
        if (c) {
            unsigned pos = atomicAdd(&g_cursor[i << 4], c);
            if (pos + c > (unsigned)((i + 1) * kCap)) { g_fb = 1; s_gbase[i] = 0xFFFFFFFFu; }
            else s_gbase[i] = pos;
        }
    }
    __syncthreads();   // s_gbase visible to all
    // direct global writes (same line pattern the old copy-out produced)
#pragma unroll
    for (int e = 0; e < 16; ++e) {
        if (val[e]) {
            unsigned gb = s_gbase[flu[e] >> 12];
            if (gb != 0xFFFFFFFFu) {
                const int k = e >> 2, j = e & 3;
                unsigned idx = (unsigned)(((g0 + (k << 8)) << 2) + j);
                unsigned dst = gb + rank[e];
                g_keyb[dst] = ((unsigned long long)hb[e] << 32) | idx;
                g_cellb[dst] = (unsigned short)(flu[e] & 4095u);
            }
        }
    }
}

__global__ void k_gate() {
    if (threadIdx.x == 0 && blockIdx.x == 0) {
        if (!okfast()) g_fb = 1;
    }
}

// Per-bucket LDS reduce: max hbits per cell, then min idx among bit-equal
// maxers (== ref's two-scatter). Winners straight to out (pre-zeroed).
__global__ void __launch_bounds__(256) k_reduce(int n, float* __restrict__ out) {
    if (g_fb) return;
    __shared__ unsigned s_hmax[4096], s_imin[4096];
    const int tid = threadIdx.x;
    const int bk = blockIdx.x;
    for (int i = tid; i < 4096; i += 256) { s_hmax[i] = 0u; s_imin[i] = 0xFFFFFFFFu; }
    __syncthreads();
    const unsigned lo = (unsigned)(bk * kCap);
    unsigned hi = g_cursor[bk << 4];
    const unsigned cap = (unsigned)((bk + 1) * kCap);
    if (hi > cap) hi = cap;
    for (unsigned i = lo + tid; i < hi; i += 256)
        atomicMax(&s_hmax[g_cellb[i]], (unsigned)(g_keyb[i] >> 32));
    __syncthreads();
    for (unsigned i = lo + tid; i < hi; i += 256) {
        unsigned long long k = g_keyb[i];
        unsigned c = g_cellb[i];
        if ((unsigned)(k >> 32) == s_hmax[c])
            atomicMin(&s_imin[c], (unsigned)k);
    }
    __syncthreads();
    for (int c = tid; c < 4096; c += 256) {
        unsigned im = s_imin[c];
        if (im != 0xFFFFFFFFu) {
            out[im] = __uint_as_float(s_hmax[c]);   // [0,n) kept_heights
            out[n + im] = 1.0f;                     // [n,2n) keep
        }
    }
}

// ---- gated fallback chain (exact R14 logic; runs only if g_fb) ----
__global__ void k_fb_zero() {
    if (!g_fb) return;
    int i = blockIdx.x * blockDim.x + threadIdx.x;
    int stride = gridDim.x * blockDim.x;
    for (int c = i; c < kNumCells; c += stride) g_cell[c] = 0ULL;
}
__global__ void k_fb_scatter(const float* __restrict__ xyz,
                             const int* __restrict__ bidx, int n) {
    if (!g_fb) return;
    const int minr = g_minr, minc = g_minc;
    const int rmax = g_maxr - minr, cmax = g_maxc - minc;
    int t = blockIdx.x * blockDim.x + threadIdx.x;
    int S = gridDim.x * blockDim.x;
    for (int i = t; i < n; i += S) {
        float x = xyz[3 * i + 0], h = xyz[3 * i + 1], z = xyz[3 * i + 2];
        int qr = quant(z) - minr, qc = quant(x) - minc;
        int flat = bidx[i] * (rmax * cmax) + qr * cmax + qc;
        if (flat >= 0 && flat < kNumCells) {
            unsigned long long key =
                ((unsigned long long)__float_as_uint(h) << 32) | (unsigned)(~i);
            if (key > g_cell[flat]) atomicMax(&g_cell[flat], key);
        }
    }
}
__global__ void k_fb_fin(int n, float* __restrict__ out) {
    if (!g_fb) return;
    int i = blockIdx.x * blockDim.x + threadIdx.x;
    int stride = gridDim.x * blockDim.x;
    for (int c = i; c < kNumCells; c += stride) {
        unsigned long long key = g_cell[c];
        if (key == 0ULL) continue;
        unsigned winner = ~(unsigned)key;
        out[winner] = __uint_as_float((unsigned)(key >> 32));
        out[n + winner] = 1.0f;
    }
}
__global__ void k_reset() {
    if (threadIdx.x == 0 && blockIdx.x == 0) {
        g_fb = 0;
        g_minr = INT_MAX; g_maxr = INT_MIN;
        g_minc = INT_MAX; g_maxc = INT_MIN;
    }
}

extern "C" void kernel_launch(void* const* d_in, const int* in_sizes, int n_in,
                              void* d_out, int out_size, void* d_ws, size_t ws_size,
                              hipStream_t stream) {
    const float* xyz = (const float*)d_in[0];
    const int* bidx = (const int*)d_in[1];
    // d_in[2] (semantics) unused by the reference.
    int n = in_sizes[1];

    const int B = 256;
    const int zb = 512;
    int gridMain = zb + ((n + 4095) >> 12);     // 512 + 2048
    k_cursor<<<(kNBk + B - 1) / B, B, 0, stream>>>();
    k_main<<<gridMain, B, 0, stream>>>(xyz, bidx, n, (float*)d_out, out_size, zb);
    k_gate<<<1, 64, 0, stream>>>();
    k_reduce<<<kNBk, B, 0, stream>>>(n, (float*)d_out);
    k_fb_zero<<<2048, B, 0, stream>>>();
    k_fb_scatter<<<4096, B, 0, stream>>>(xyz, bidx, n);
    k_fb_fin<<<2048, B, 0, stream>>>(n, (float*)d_out);
    k_reset<<<1, 64, 0, stream>>>();
}